// Round 11
// baseline (698.359 us; speedup 1.0000x reference)
//
#include <hip/hip_runtime.h>
#include <hip/hip_bf16.h>

typedef __bf16 bf16x8 __attribute__((ext_vector_type(8)));
typedef float f32x4 __attribute__((ext_vector_type(4)));

constexpr int SEQ    = 128;
constexpr int NVOCAB = 32000;

// ---------------- workspace layout (float offsets) ----------------
constexpr size_t O_HA = 0;                          // [128][256]
constexpr size_t O_HB = O_HA + (size_t)SEQ*256;     // [128][256]
constexpr size_t O_U  = O_HB + (size_t)SEQ*256;     // [128][512]
constexpr size_t O_DT = O_U  + (size_t)SEQ*512;     // [128][512]
constexpr size_t O_ZS = O_DT + (size_t)SEQ*512;     // [128][512] silu(z)
constexpr size_t O_BC = O_ZS + (size_t)SEQ*512;     // [128][32]
constexpr size_t O_YG = O_BC + (size_t)SEQ*32;      // [128][512]
constexpr size_t O_AH = O_YG + (size_t)SEQ*512;     // [128][256] bf16 (uses half)
constexpr size_t O_EB = O_AH + (size_t)SEQ*256;     // emb bf16: 8.192M bf16 = 4.096M floats

__device__ __forceinline__ float wsum(float p) {
    #pragma unroll
    for (int m = 1; m < 64; m <<= 1) p += __shfl_xor(p, m);
    return p;
}
__device__ __forceinline__ float dot4(float4 a, float4 b) {
    return a.x*b.x + a.y*b.y + a.z*b.z + a.w*b.w;
}

// ---------------- K-split register-W mini-GEMM (8 waves, 512 threads) ----------------
// dest[r][c] = sum_k A[r][k]*Wg[c*KK+k] (+addsrc) (+bias), c=0..255.
// Wave wv: kg=wv>>2 (K-half), cg=wv&3 (64-col group). Lane (cs,tq): 4 cols
// c0=cg*64+cs*4, k-slice tq*4 within 16-chunks of its K-half.
// W global->register, explicit even/odd prefetch (static indexing only; round-7
// lesson: runtime-indexed register arrays are forbidden).
// A: LDS float4 reads, broadcast across the 16 cs lanes (conflict-free).
// Partials reduced via pb LDS ([kg*MR+r][c], stride-1 -> conflict-free).
// Internal __syncthreads (all threads must call); caller syncs before reading dest.
template<int MR, int KK>
__device__ __forceinline__ void gemmT(
    const float* __restrict__ Wg, const float* __restrict__ A, int AS,
    float* __restrict__ pb, float* __restrict__ dest, int DS,
    const float* __restrict__ addsrc, int ASS, const float* __restrict__ bias)
{
    const int tid  = threadIdx.x;
    const int lane = tid & 63;
    const int wv   = tid >> 6;           // 0..7
    const int kg   = wv >> 2;            // K-half
    const int cg   = wv & 3;             // col-quarter
    const int tq = lane & 3, cs = lane >> 2;
    const int c0 = cg*64 + cs*4;
    constexpr int KH  = KK/2;
    constexpr int NCH = KH/16;           // 8 (KK=256) or 16 (KK=512); always even
    const int kb = kg*KH;
    const float* W0 = Wg + (size_t)(c0+0)*KK + kb + tq*4;
    const float* W1 = Wg + (size_t)(c0+1)*KK + kb + tq*4;
    const float* W2 = Wg + (size_t)(c0+2)*KK + kb + tq*4;
    const float* W3 = Wg + (size_t)(c0+3)*KK + kb + tq*4;

    float acc[MR][4];
    #pragma unroll
    for (int r = 0; r < MR; ++r)
        #pragma unroll
        for (int j = 0; j < 4; ++j) acc[r][j] = 0.0f;

    float4 e0 = *(const float4*)(W0);
    float4 e1 = *(const float4*)(W1);
    float4 e2 = *(const float4*)(W2);
    float4 e3 = *(const float4*)(W3);
    float4 o0, o1, o2, o3;

    #pragma unroll
    for (int ch = 0; ch < NCH; ch += 2) {
        o0 = *(const float4*)(W0 + (ch+1)*16);
        o1 = *(const float4*)(W1 + (ch+1)*16);
        o2 = *(const float4*)(W2 + (ch+1)*16);
        o3 = *(const float4*)(W3 + (ch+1)*16);
        #pragma unroll
        for (int r = 0; r < MR; ++r) {
            float4 a = *(const float4*)&A[r*AS + kb + ch*16 + tq*4];
            acc[r][0] += dot4(a, e0);
            acc[r][1] += dot4(a, e1);
            acc[r][2] += dot4(a, e2);
            acc[r][3] += dot4(a, e3);
        }
        if (ch + 2 < NCH) {
            e0 = *(const float4*)(W0 + (ch+2)*16);
            e1 = *(const float4*)(W1 + (ch+2)*16);
            e2 = *(const float4*)(W2 + (ch+2)*16);
            e3 = *(const float4*)(W3 + (ch+2)*16);
        }
        #pragma unroll
        for (int r = 0; r < MR; ++r) {
            float4 a = *(const float4*)&A[r*AS + kb + (ch+1)*16 + tq*4];
            acc[r][0] += dot4(a, o0);
            acc[r][1] += dot4(a, o1);
            acc[r][2] += dot4(a, o2);
            acc[r][3] += dot4(a, o3);
        }
    }
    #pragma unroll
    for (int r = 0; r < MR; ++r)
        #pragma unroll
        for (int j = 0; j < 4; ++j) {
            float v = acc[r][j];
            v += __shfl_xor(v, 1);
            v += __shfl_xor(v, 2);
            acc[r][j] = v;
        }
    if (tq == 0) {
        #pragma unroll
        for (int r = 0; r < MR; ++r)
            #pragma unroll
            for (int j = 0; j < 4; ++j)
                pb[(kg*MR + r)*256 + c0 + j] = acc[r][j];
    }
    __syncthreads();
    if (tid < 256) {
        int c = tid;
        #pragma unroll
        for (int r = 0; r < MR; ++r) {
            float v = pb[r*256 + c] + pb[(MR + r)*256 + c];
            if (bias)   v += bias[c];
            if (addsrc) v += addsrc[r*ASS + c];
            dest[r*DS + c] = v;
        }
    }
}

// LayerNorm of one 256-float row by one wave: dst = (src-mean)*rstd*w + b
__device__ __forceinline__ void ln_row(const float* __restrict__ src, float* __restrict__ dst,
                                       const float* __restrict__ w, const float* __restrict__ b)
{
    int lane = threadIdx.x & 63;
    float4 x = *(const float4*)&src[lane*4];
    float sm = wsum(x.x + x.y + x.z + x.w);
    float mean = sm * (1.0f/256.0f);
    float d0 = x.x-mean, d1 = x.y-mean, d2 = x.z-mean, d3 = x.w-mean;
    float var = wsum(d0*d0 + d1*d1 + d2*d2 + d3*d3) * (1.0f/256.0f);
    float rstd = rsqrtf(var + 1e-5f);
    float4 ww = *(const float4*)&w[lane*4];
    float4 bb = *(const float4*)&b[lane*4];
    float4 o;
    o.x = d0*rstd*ww.x + bb.x;
    o.y = d1*rstd*ww.y + bb.y;
    o.z = d2*rstd*ww.z + bb.z;
    o.w = d3*rstd*ww.w + bb.w;
    *(float4*)&dst[lane*4] = o;
}

// ---------------- emb f32 -> bf16 conversion (once per launch) ----------------
__global__ __launch_bounds__(256) void cvt_emb_kernel(const float* __restrict__ e,
                                                      __hip_bfloat16* __restrict__ o)
{
    size_t base = (size_t)(blockIdx.x * 256 + threadIdx.x) * 16;
    #pragma unroll
    for (int j = 0; j < 16; j += 4) {
        float4 v = *(const float4*)&e[base + j];
        o[base + j + 0] = __float2bfloat16(v.x);
        o[base + j + 1] = __float2bfloat16(v.y);
        o[base + j + 2] = __float2bfloat16(v.z);
        o[base + j + 3] = __float2bfloat16(v.w);
    }
}

// ---------------- rowk: per-row fused layer-boundary kernel (512 threads) ----------------
// Block r: rebuild h rows r-3..r (KC of layer li-1, redundantly), write h[r];
// then KA of layer li: LN1 + in_proj + conv + silu + x_proj + dt_proj.
// __launch_bounds__(512, 2): 2 waves/EU = one 8-wave block per CU -> VGPR cap 256,
// eliminating the 65536-per-block budget spill (round-10 lesson: VGPR_Count=128,
// WRITE_SIZE=15.2MB scratch traffic at default heuristics).
__global__ __launch_bounds__(512, 2) void rowk_kernel(
    const int* __restrict__ x, const float* __restrict__ emb,
    const float* __restrict__ n1w_l, const float* __restrict__ n1b_l,
    const float* __restrict__ n2w_l, const float* __restrict__ n2b_l,
    const float* __restrict__ ipw_l, const float* __restrict__ cw_l, const float* __restrict__ cb_l,
    const float* __restrict__ xpw_l, const float* __restrict__ dpw_l, const float* __restrict__ dpb_l,
    const float* __restrict__ opw_l, const float* __restrict__ aivw_l, const float* __restrict__ aivb_l,
    const float* __restrict__ aow_l, const float* __restrict__ aob_l,
    const float* __restrict__ nfw, const float* __restrict__ nfb,
    const float* __restrict__ hin, float* __restrict__ hout,
    const float* __restrict__ ygv, float* __restrict__ uv, float* __restrict__ dtv,
    float* __restrict__ zsv, float* __restrict__ bcv, __hip_bfloat16* __restrict__ AHb,
    int li)
{
    __shared__ float SM[8384];                  // 32.75 KB
    float* hP  = SM;                            // [4][264] h_prev rows
    float* h1  = SM + 1056;                     // [4][264] h_cur rows
    float* sLN = SM + 2112;                     // [4][264]
    float* sAX = SM + 3168;                     // [4][520] yg / v / u-raw
    float* zR  = SM + 5248;                     // [512]
    float* suR = SM + 5760;                     // [512]
    float* sxR = SM + 6272;                     // [64]
    float* pb  = SM + 6336;                     // [8][256] gemm partials

    const int r = blockIdx.x;
    const int tid = threadIdx.x;
    const int lane = tid & 63, wv = tid >> 6;
    int rr[4];
    #pragma unroll
    for (int j = 0; j < 4; ++j) { int v = r - 3 + j; rr[j] = v < 0 ? 0 : v; }

    // ---- h_prev rows r-3..r ----
    #pragma unroll
    for (int j = 0; j < 2; ++j) {
        int idx = j*512 + tid;
        int hr = idx >> 8, hc = idx & 255;
        if (li <= 1) hP[hr*264 + hc] = emb[(size_t)x[rr[hr]]*256 + hc];
        else         hP[hr*264 + hc] = hin[rr[hr]*256 + hc];
    }
    __syncthreads();

    float* hC = hP;
    if (li >= 1) {
        // ---- KC (layer li-1): out_proj + resid ; LN2 ; v ; attn_out + resid ----
        #pragma unroll
        for (int j = 0; j < 4; ++j)
            sAX[j*520 + tid] = ygv[rr[j]*512 + tid];
        __syncthreads();
        gemmT<4,512>(opw_l, sAX, 520, pb, h1, 264, hP, 264, nullptr);    // h1 = hP + op(yg)
        __syncthreads();
        if (wv < 4) ln_row(h1 + wv*264, sLN + wv*264, n2w_l, n2b_l);
        __syncthreads();
        gemmT<4,256>(aivw_l, sLN, 264, pb, sAX, 520, nullptr, 0, aivb_l); // v
        __syncthreads();
        gemmT<4,256>(aow_l, sAX, 520, pb, h1, 264, h1, 264, aob_l);       // h1 += ao(v)+b
        __syncthreads();
        hC = h1;
        if (tid < 256) hout[r*256 + tid] = h1[3*264 + tid];
        if (li == 6) {
            if (tid < 256) {
                float v = h1[3*264 + tid];
                float s = wsum(v);
                float q = wsum(v*v);
                if (lane == 0) { sxR[wv] = s; sxR[8 + wv] = q; }
            }
            __syncthreads();
            if (tid < 256) {
                float v = h1[3*264 + tid];
                float mean = (sxR[0]+sxR[1]+sxR[2]+sxR[3]) * (1.0f/256.0f);
                float var  = (sxR[8]+sxR[9]+sxR[10]+sxR[11]) * (1.0f/256.0f) - mean*mean;
                float rstd = rsqrtf(var + 1e-5f);
                AHb[r*256 + tid] = __float2bfloat16((v - mean)*rstd*nfw[tid] + nfb[tid]);
            }
            return;
        }
    }

    // ---- KA (layer li) ----
    if (wv < 4) ln_row(hC + wv*264, sLN + wv*264, n1w_l, n1b_l);
    __syncthreads();
    gemmT<4,256>(ipw_l,                   sLN, 264, pb, sAX,       520, nullptr, 0, nullptr);
    __syncthreads();
    gemmT<4,256>(ipw_l + (size_t)256*256, sLN, 264, pb, sAX + 256, 520, nullptr, 0, nullptr);
    __syncthreads();
    gemmT<1,256>(ipw_l + (size_t)512*256, sLN + 3*264, 264, pb, zR,       512, nullptr, 0, nullptr);
    __syncthreads();
    gemmT<1,256>(ipw_l + (size_t)768*256, sLN + 3*264, 264, pb, zR + 256, 512, nullptr, 0, nullptr);
    __syncthreads();

    // conv + bias + silu -> suR, u[r] ; zs[r] = silu(z)
    {
        int d = tid;
        float4 c4 = *(const float4*)&cw_l[d*4];
        float acc = cb_l[d];
        if (r >= 3) acc += sAX[d]        * c4.x;
        if (r >= 2) acc += sAX[520 + d]  * c4.y;
        if (r >= 1) acc += sAX[1040 + d] * c4.z;
        acc += sAX[1560 + d] * c4.w;
        float sg = acc / (1.0f + __expf(-acc));
        suR[d] = sg;
        uv[r*512 + d] = sg;
        float z = zR[d];
        zsv[r*512 + d] = z / (1.0f + __expf(-z));
    }
    __syncthreads();

    // x_proj (48 cols, K=512): 8 waves x 6 cols
    {
        float4 a0 = *(const float4*)&suR[lane*4];
        float4 a1 = *(const float4*)&suR[256 + lane*4];
        float p[6];
        #pragma unroll
        for (int j = 0; j < 6; ++j) {
            int c = wv*6 + j;
            float4 q0 = *(const float4*)&xpw_l[(size_t)c*512 + lane*4];
            float4 q1 = *(const float4*)&xpw_l[(size_t)c*512 + 256 + lane*4];
            p[j] = dot4(a0, q0) + dot4(a1, q1);
        }
        #pragma unroll
        for (int m = 1; m < 64; m <<= 1) {
            #pragma unroll
            for (int j = 0; j < 6; ++j) p[j] += __shfl_xor(p[j], m);
        }
        if (lane == 0) {
            #pragma unroll
            for (int j = 0; j < 6; ++j) sxR[wv*6 + j] = p[j];
        }
    }
    __syncthreads();
    if (tid >= 16 && tid < 48) bcv[r*32 + tid - 16] = sxR[tid];

    // dt_proj + bias + softplus
    {
        int d = tid;
        float4 sx0 = *(const float4*)&sxR[0];
        float4 sx1 = *(const float4*)&sxR[4];
        float4 sx2 = *(const float4*)&sxR[8];
        float4 sx3 = *(const float4*)&sxR[12];
        const float4* dp = (const float4*)&dpw_l[(size_t)d*16];
        float acc = dpb_l[d] + dot4(dp[0], sx0) + dot4(dp[1], sx1)
                             + dot4(dp[2], sx2) + dot4(dp[3], sx3);
        dtv[r*512 + d] = fmaxf(acc, 0.0f) + log1pf(__expf(-fabsf(acc)));
    }
}

// ---------------- selective scan + skip + gate (verified structure) ----------------
__global__ __launch_bounds__(256) void scan_kernel(
    const float* __restrict__ dt, const float* __restrict__ u, const float* __restrict__ zs,
    const float* __restrict__ bcv,
    const float* __restrict__ alog_l, const float* __restrict__ dsk_l,
    float* __restrict__ yg)
{
    __shared__ float s5[5*128];
    float* sdt = s5;        float* su2 = s5 + 128;
    float* sz2 = s5 + 256;  float* sB  = s5 + 384;  float* sC = s5 + 512;
    int tid = threadIdx.x;
    int s  = tid & 15, dl = tid >> 4;
    int d0 = blockIdx.x * 16;
    int d  = d0 + dl;
    float a_ds = -__expf(alog_l[d*16 + s]);
    float dskv = dsk_l[d];
    float hst = 0.0f;
    for (int t0 = 0; t0 < SEQ; t0 += 8) {
        __syncthreads();
        if (tid < 128) {
            int tt = tid >> 4, j = tid & 15;
            int t = t0 + tt;
            sdt[tt*16+j] = dt[t*512 + d0 + j];
            su2[tt*16+j] = u [t*512 + d0 + j];
            sz2[tt*16+j] = zs[t*512 + d0 + j];
        } else {
            int q = tid - 128;
            int tt = q >> 4, j = q & 15;
            int t = t0 + tt;
            sB[tt*16+j] = bcv[t*32 + j];
            sC[tt*16+j] = bcv[t*32 + 16 + j];
        }
        __syncthreads();
        #pragma unroll
        for (int tt = 0; tt < 8; ++tt) {
            float dtvv = sdt[tt*16+dl];
            float uvv  = su2[tt*16+dl];
            hst = __expf(dtvv * a_ds) * hst + dtvv * uvv * sB[tt*16+s];
            float p = hst * sC[tt*16+s];
            p += __shfl_xor(p, 1);
            p += __shfl_xor(p, 2);
            p += __shfl_xor(p, 4);
            p += __shfl_xor(p, 8);
            if (s == 0) {
                float y = p + uvv * dskv;
                yg[(t0+tt)*512 + d] = y * sz2[tt*16+dl];
            }
        }
    }
}

// ---------------- head GEMM via bf16 MFMA: out(128,32000) = AH @ emb^T + hb ----------------
__global__ __launch_bounds__(256) void head_mfma_kernel(
    const __hip_bfloat16* __restrict__ AHb, const __hip_bfloat16* __restrict__ Eb,
    const float* __restrict__ hb, float* __restrict__ out)
{
    int tid = threadIdx.x;
    int lane = tid & 63;
    int wv = tid >> 6;
    int mbase = blockIdx.y * 16;
    int nbase = blockIdx.x * 64 + wv * 16;
    int m = mbase + (lane & 15);
    int n = nbase + (lane & 15);
    int k0 = (lane >> 4) * 8;
    const __bf16* Ap = (const __bf16*)AHb + m*256 + k0;
    const __bf16* Bp = (const __bf16*)Eb + (size_t)n*256 + k0;
    f32x4 acc = {0.0f, 0.0f, 0.0f, 0.0f};
    #pragma unroll
    for (int kb = 0; kb < 256; kb += 32) {
        bf16x8 a  = *(const bf16x8*)(Ap + kb);
        bf16x8 bb = *(const bf16x8*)(Bp + kb);
        acc = __builtin_amdgcn_mfma_f32_16x16x32_bf16(a, bb, acc, 0, 0, 0);
    }
    int col = lane & 15;
    int rq = lane >> 4;
    float bias = hb[nbase + col];
    #pragma unroll
    for (int i = 0; i < 4; ++i)
        out[(size_t)(mbase + rq*4 + i)*NVOCAB + nbase + col] = acc[i] + bias;
}

// ---------------- launch (15 nodes) ----------------
extern "C" void kernel_launch(void* const* d_in, const int* in_sizes, int n_in,
                              void* d_out, int out_size, void* d_ws, size_t ws_size,
                              hipStream_t stream)
{
    const int*   xin = (const int*)d_in[0];
    const float* emb = (const float*)d_in[1];
    const float* n1w = (const float*)d_in[2];
    const float* n1b = (const float*)d_in[3];
    const float* n2w = (const float*)d_in[4];
    const float* n2b = (const float*)d_in[5];
    const float* ipw = (const float*)d_in[6];
    const float* cw  = (const float*)d_in[7];
    const float* cb  = (const float*)d_in[8];
    const float* xpw = (const float*)d_in[9];
    const float* dpw = (const float*)d_in[10];
    const float* dpb = (const float*)d_in[11];
    const float* alog= (const float*)d_in[12];
    const float* dsk = (const float*)d_in[13];
    const float* opw = (const float*)d_in[14];
    const float* aiw = (const float*)d_in[15];
    const float* aib = (const float*)d_in[16];
    const float* aow = (const float*)d_in[17];
    const float* aob = (const float*)d_in[18];
    const float* nfw = (const float*)d_in[19];
    const float* nfb = (const float*)d_in[20];
    const float* hb  = (const float*)d_in[21];
    float* ws  = (float*)d_ws;
    float* out = (float*)d_out;

    __hip_bfloat16* AHb = (__hip_bfloat16*)(ws + O_AH);
    __hip_bfloat16* Eb  = (__hip_bfloat16*)(ws + O_EB);

    // emb -> bf16 (32000*256 = 2000*256*16)
    cvt_emb_kernel<<<2000, 256, 0, stream>>>(emb, Eb);

    for (int i = 0; i <= 6; ++i) {
        int ka = i <= 5 ? i : 5;          // KA layer (unused when i==6)
        int kc = i >= 1 ? i - 1 : 0;      // KC layer (unused when i==0)
        const float* hin  = (i % 2 == 0) ? ws + O_HA : ws + O_HB;
        float*       hout = (i % 2 == 0) ? ws + O_HB : ws + O_HA;
        rowk_kernel<<<128, 512, 0, stream>>>(
            xin, emb,
            n1w + ka*256, n1b + ka*256,
            n2w + kc*256, n2b + kc*256,
            ipw + (size_t)ka*1024*256, cw + (size_t)ka*512*4, cb + ka*512,
            xpw + (size_t)ka*48*512, dpw + (size_t)ka*512*16, dpb + ka*512,
            opw + (size_t)kc*256*512,
            aiw + (size_t)kc*768*256 + (size_t)512*256, aib + kc*768 + 512,
            aow + (size_t)kc*256*256, aob + kc*256,
            nfw, nfb,
            hin, hout,
            ws + O_YG, ws + O_U, ws + O_DT, ws + O_ZS, ws + O_BC, AHb,
            i);
        if (i <= 5)
            scan_kernel<<<32, 256, 0, stream>>>(
                ws + O_DT, ws + O_U, ws + O_ZS, ws + O_BC,
                alog + (size_t)i*512*16, dsk + i*512, ws + O_YG);
    }
    head_mfma_kernel<<<dim3(NVOCAB/64, SEQ/16), 256, 0, stream>>>(AHb, Eb, hb, out);
}

// Round 12
// 601.392 us; speedup vs baseline: 1.1612x; 1.1612x over previous
//
#include <hip/hip_runtime.h>
#include <hip/hip_bf16.h>

typedef __bf16 bf16x8 __attribute__((ext_vector_type(8)));
typedef float f32x4 __attribute__((ext_vector_type(4)));
typedef __hip_bfloat16 hbf;

constexpr int SEQ    = 128;
constexpr int NVOCAB = 32000;

// ---------------- workspace layout (float offsets) ----------------
constexpr size_t O_HA = 0;                          // [128][256]
constexpr size_t O_HB = O_HA + (size_t)SEQ*256;     // [128][256]
constexpr size_t O_U  = O_HB + (size_t)SEQ*256;     // [128][512]
constexpr size_t O_DT = O_U  + (size_t)SEQ*512;     // [128][512]
constexpr size_t O_ZS = O_DT + (size_t)SEQ*512;     // [128][512] silu(z)
constexpr size_t O_BC = O_ZS + (size_t)SEQ*512;     // [128][32]
constexpr size_t O_YG = O_BC + (size_t)SEQ*32;      // [128][512]
constexpr size_t O_AH = O_YG + (size_t)SEQ*512;     // [128][256] bf16 (uses half)
constexpr size_t O_EB = O_AH + (size_t)SEQ*256;     // emb bf16: 8.192M elems = 4.096M floats
constexpr size_t O_WIP= O_EB + (size_t)NVOCAB*256/2;       // ipw bf16 [6][1024][256]
constexpr size_t O_WOP= O_WIP+ (size_t)6*1024*256/2;       // opw bf16 [6][256][512]
constexpr size_t O_WAV= O_WOP+ (size_t)6*256*512/2;        // attn-v bf16 [6][256][256]
constexpr size_t O_WAO= O_WAV+ (size_t)6*256*256/2;        // attn-out bf16 [6][256][256]

__device__ __forceinline__ float wsum(float p) {
    #pragma unroll
    for (int m = 1; m < 64; m <<= 1) p += __shfl_xor(p, m);
    return p;
}
__device__ __forceinline__ float dot4(float4 a, float4 b) {
    return a.x*b.x + a.y*b.y + a.z*b.z + a.w*b.w;
}

// ---------------- MFMA mini-GEMM: D(4 x NT) = A(4 x KK) @ Wb(NT x KK)^T ----------------
// mfma_f32_16x16x32_bf16 per 16-col tile; wave wv owns tiles wv*TPW..+TPW-1 over full K.
// A: LDS bf16, row stride ASb; lanes read row (lane&3) -> D rows 0-3 valid (in lanes 0-15),
// rows 4-15 are duplicates, discarded. B-frag: one 16B global load per lane per MFMA.
// Epilogue by lanes 0-15: dest f32 (stride DS) and/or destb bf16; optional addsrc/bias.
// R3: write only row 3 to dest[c] (z-projection). No internal syncs; caller syncs.
template<int KK, int NT, bool R3>
__device__ __forceinline__ void gemmM(
    const hbf* __restrict__ Wb, const hbf* __restrict__ Ab, int ASb,
    float* __restrict__ dest, int DS, hbf* __restrict__ destb, int DSB,
    const float* __restrict__ addsrc, int ASS, const float* __restrict__ bias)
{
    constexpr int TPW = NT/128;          // tiles per wave (2 or 4)
    constexpr int NCH = KK/32;           // mfma steps (8 or 16)
    const int lane = threadIdx.x & 63;
    const int wv   = threadIdx.x >> 6;   // 0..7
    const int col  = lane & 15;
    const int kq   = lane >> 4;          // 0..3
    const __bf16* Ap = (const __bf16*)Ab + (lane & 3)*ASb + kq*8;
    const __bf16* Wp = (const __bf16*)Wb + (size_t)(wv*TPW*16 + col)*KK + kq*8;
    f32x4 acc[TPW];
    #pragma unroll
    for (int t = 0; t < TPW; ++t) acc[t] = (f32x4){0.f,0.f,0.f,0.f};
    #pragma unroll
    for (int ch = 0; ch < NCH; ++ch) {
        bf16x8 a = *(const bf16x8*)(Ap + ch*32);
        #pragma unroll
        for (int t = 0; t < TPW; ++t) {
            bf16x8 b = *(const bf16x8*)(Wp + (size_t)t*16*KK + ch*32);
            acc[t] = __builtin_amdgcn_mfma_f32_16x16x32_bf16(a, b, acc[t], 0, 0, 0);
        }
    }
    if (lane < 16) {
        #pragma unroll
        for (int t = 0; t < TPW; ++t) {
            int c = (wv*TPW + t)*16 + col;
            float bv = bias ? bias[c] : 0.0f;
            #pragma unroll
            for (int i = 0; i < 4; ++i) {
                float v = acc[t][i] + bv;
                if (addsrc) v += addsrc[i*ASS + c];
                if (R3) {
                    if (i == 3) dest[c] = v;
                } else {
                    if (dest)  dest[i*DS + c] = v;
                    if (destb) destb[i*DSB + c] = __float2bfloat16(v);
                }
            }
        }
    }
}

// LayerNorm of one 256-float row by one wave -> bf16 row
__device__ __forceinline__ void ln_row_b(const float* __restrict__ src, hbf* __restrict__ dstb,
                                         const float* __restrict__ w, const float* __restrict__ b)
{
    int lane = threadIdx.x & 63;
    float4 x = *(const float4*)&src[lane*4];
    float sm = wsum(x.x + x.y + x.z + x.w);
    float mean = sm * (1.0f/256.0f);
    float d0 = x.x-mean, d1 = x.y-mean, d2 = x.z-mean, d3 = x.w-mean;
    float var = wsum(d0*d0 + d1*d1 + d2*d2 + d3*d3) * (1.0f/256.0f);
    float rstd = rsqrtf(var + 1e-5f);
    float4 ww = *(const float4*)&w[lane*4];
    float4 bb = *(const float4*)&b[lane*4];
    dstb[lane*4+0] = __float2bfloat16(d0*rstd*ww.x + bb.x);
    dstb[lane*4+1] = __float2bfloat16(d1*rstd*ww.y + bb.y);
    dstb[lane*4+2] = __float2bfloat16(d2*rstd*ww.z + bb.z);
    dstb[lane*4+3] = __float2bfloat16(d3*rstd*ww.w + bb.w);
}

// ---------------- emb f32 -> bf16 (once per launch) ----------------
__global__ __launch_bounds__(256) void cvt_emb_kernel(const float* __restrict__ e,
                                                      hbf* __restrict__ o)
{
    size_t base = (size_t)(blockIdx.x * 256 + threadIdx.x) * 16;
    #pragma unroll
    for (int j = 0; j < 16; j += 4) {
        float4 v = *(const float4*)&e[base + j];
        o[base + j + 0] = __float2bfloat16(v.x);
        o[base + j + 1] = __float2bfloat16(v.y);
        o[base + j + 2] = __float2bfloat16(v.z);
        o[base + j + 3] = __float2bfloat16(v.w);
    }
}

// ---------------- layer weights f32 -> bf16 (once per launch) ----------------
__global__ __launch_bounds__(256) void cvt_w_kernel(
    const float* __restrict__ ipw, const float* __restrict__ opw,
    const float* __restrict__ aiw, const float* __restrict__ aow,
    float* __restrict__ ws)
{
    hbf* dip = (hbf*)(ws + O_WIP);
    hbf* dop = (hbf*)(ws + O_WOP);
    hbf* dav = (hbf*)(ws + O_WAV);
    hbf* dao = (hbf*)(ws + O_WAO);
    int tid = blockIdx.x * 256 + threadIdx.x;
    int stride = gridDim.x * 256;
    for (int i = tid; i < 6*1024*256; i += stride) dip[i] = __float2bfloat16(ipw[i]);
    for (int i = tid; i < 6*256*512;  i += stride) dop[i] = __float2bfloat16(opw[i]);
    for (int i = tid; i < 6*256*256;  i += stride)
        dav[i] = __float2bfloat16(aiw[(size_t)(i >> 16)*768*256 + 512*256 + (i & 65535)]);
    for (int i = tid; i < 6*256*256;  i += stride) dao[i] = __float2bfloat16(aow[i]);
}

// ---------------- rowk: per-row fused layer-boundary kernel (512 threads, MFMA) ----------------
// Block r: rebuild h rows r-3..r (KC of layer li-1, redundantly), write h[r];
// then KA of layer li: LN1 + in_proj + conv + silu + x_proj + dt_proj.
__global__ __launch_bounds__(512) void rowk_kernel(
    const int* __restrict__ x, const float* __restrict__ emb,
    const float* __restrict__ n1w_l, const float* __restrict__ n1b_l,
    const float* __restrict__ n2w_l, const float* __restrict__ n2b_l,
    const hbf* __restrict__ ipb_l, const float* __restrict__ cw_l, const float* __restrict__ cb_l,
    const float* __restrict__ xpw_l, const float* __restrict__ dpw_l, const float* __restrict__ dpb_l,
    const hbf* __restrict__ opb_l, const hbf* __restrict__ avb_l, const float* __restrict__ aivb_l,
    const hbf* __restrict__ aob_wl, const float* __restrict__ aob_l,
    const float* __restrict__ nfw, const float* __restrict__ nfb,
    const float* __restrict__ hin, float* __restrict__ hout,
    const float* __restrict__ ygv, float* __restrict__ uv, float* __restrict__ dtv,
    float* __restrict__ zsv, float* __restrict__ bcv, hbf* __restrict__ AHb,
    int li)
{
    __shared__ float SM[5280];
    float* hP  = SM;                            // [4][264] h_prev rows
    float* h1  = SM + 1056;                     // [4][264] h_cur rows
    float* sAX = SM + 2112;                     // [4][520] u-raw rows
    float* zR  = SM + 4192;                     // [512]
    float* suR = SM + 4704;                     // [512]
    float* sxR = SM + 5216;                     // [64]
    __shared__ __align__(16) hbf SB[4192];
    hbf* sYb  = SB;                             // [4][520] yg bf16
    hbf* sLNb = SB + 2080;                      // [4][264] LN2 / LN1 bf16 (reused)
    hbf* sVb  = SB + 3136;                      // [4][264] v bf16

    const int r = blockIdx.x;
    const int tid = threadIdx.x;
    const int lane = tid & 63, wv = tid >> 6;
    int rr[4];
    #pragma unroll
    for (int j = 0; j < 4; ++j) { int v = r - 3 + j; rr[j] = v < 0 ? 0 : v; }

    // ---- h_prev rows r-3..r ----
    #pragma unroll
    for (int j = 0; j < 2; ++j) {
        int idx = j*512 + tid;
        int hr = idx >> 8, hc = idx & 255;
        if (li <= 1) hP[hr*264 + hc] = emb[(size_t)x[rr[hr]]*256 + hc];
        else         hP[hr*264 + hc] = hin[rr[hr]*256 + hc];
    }
    __syncthreads();

    float* hC = hP;
    if (li >= 1) {
        // ---- KC (layer li-1): out_proj + resid ; LN2 ; v ; attn_out + resid ----
        #pragma unroll
        for (int j = 0; j < 4; ++j)
            sYb[j*520 + tid] = __float2bfloat16(ygv[rr[j]*512 + tid]);
        __syncthreads();
        gemmM<512,256,false>(opb_l, sYb, 520, h1, 264, nullptr, 0, hP, 264, nullptr);
        __syncthreads();
        if (wv < 4) ln_row_b(h1 + wv*264, sLNb + wv*264, n2w_l, n2b_l);
        __syncthreads();
        gemmM<256,256,false>(avb_l, sLNb, 264, nullptr, 0, sVb, 264, nullptr, 0, aivb_l);
        __syncthreads();
        gemmM<256,256,false>(aob_wl, sVb, 264, h1, 264, nullptr, 0, h1, 264, aob_l);
        __syncthreads();
        hC = h1;
        if (tid < 256) hout[r*256 + tid] = h1[3*264 + tid];
        if (li == 6) {
            if (tid < 256) {
                float v = h1[3*264 + tid];
                float s = wsum(v);
                float q = wsum(v*v);
                if (lane == 0) { sxR[wv] = s; sxR[8 + wv] = q; }
            }
            __syncthreads();
            if (tid < 256) {
                float v = h1[3*264 + tid];
                float mean = (sxR[0]+sxR[1]+sxR[2]+sxR[3]) * (1.0f/256.0f);
                float var  = (sxR[8]+sxR[9]+sxR[10]+sxR[11]) * (1.0f/256.0f) - mean*mean;
                float rstd = rsqrtf(var + 1e-5f);
                AHb[r*256 + tid] = __float2bfloat16((v - mean)*rstd*nfw[tid] + nfb[tid]);
            }
            return;
        }
    }

    // ---- KA (layer li) ----
    if (wv < 4) ln_row_b(hC + wv*264, sLNb + wv*264, n1w_l, n1b_l);
    __syncthreads();
    // in_proj u-half (4 rows x 512 cols) and z-half (row 3 only kept)
    gemmM<256,512,false>(ipb_l,                   sLNb, 264, sAX, 520, nullptr, 0, nullptr, 0, nullptr);
    gemmM<256,512,true >(ipb_l + (size_t)512*256, sLNb, 264, zR,  0,   nullptr, 0, nullptr, 0, nullptr);
    __syncthreads();

    // conv + bias + silu -> suR, u[r] ; zs[r] = silu(z)
    {
        int d = tid;
        float4 c4 = *(const float4*)&cw_l[d*4];
        float acc = cb_l[d];
        if (r >= 3) acc += sAX[d]        * c4.x;
        if (r >= 2) acc += sAX[520 + d]  * c4.y;
        if (r >= 1) acc += sAX[1040 + d] * c4.z;
        acc += sAX[1560 + d] * c4.w;
        float sg = acc / (1.0f + __expf(-acc));
        suR[d] = sg;
        uv[r*512 + d] = sg;
        float z = zR[d];
        zsv[r*512 + d] = z / (1.0f + __expf(-z));
    }
    __syncthreads();

    // x_proj (48 cols, K=512, f32): 8 waves x 6 cols
    {
        float4 a0 = *(const float4*)&suR[lane*4];
        float4 a1 = *(const float4*)&suR[256 + lane*4];
        float p[6];
        #pragma unroll
        for (int j = 0; j < 6; ++j) {
            int c = wv*6 + j;
            float4 q0 = *(const float4*)&xpw_l[(size_t)c*512 + lane*4];
            float4 q1 = *(const float4*)&xpw_l[(size_t)c*512 + 256 + lane*4];
            p[j] = dot4(a0, q0) + dot4(a1, q1);
        }
        #pragma unroll
        for (int m = 1; m < 64; m <<= 1) {
            #pragma unroll
            for (int j = 0; j < 6; ++j) p[j] += __shfl_xor(p[j], m);
        }
        if (lane == 0) {
            #pragma unroll
            for (int j = 0; j < 6; ++j) sxR[wv*6 + j] = p[j];
        }
    }
    __syncthreads();
    if (tid >= 16 && tid < 48) bcv[r*32 + tid - 16] = sxR[tid];

    // dt_proj + bias + softplus (f32)
    {
        int d = tid;
        float4 sx0 = *(const float4*)&sxR[0];
        float4 sx1 = *(const float4*)&sxR[4];
        float4 sx2 = *(const float4*)&sxR[8];
        float4 sx3 = *(const float4*)&sxR[12];
        const float4* dp = (const float4*)&dpw_l[(size_t)d*16];
        float acc = dpb_l[d] + dot4(dp[0], sx0) + dot4(dp[1], sx1)
                             + dot4(dp[2], sx2) + dot4(dp[3], sx3);
        dtv[r*512 + d] = fmaxf(acc, 0.0f) + log1pf(__expf(-fabsf(acc)));
    }
}

// ---------------- selective scan + skip + gate (verified structure) ----------------
__global__ __launch_bounds__(256) void scan_kernel(
    const float* __restrict__ dt, const float* __restrict__ u, const float* __restrict__ zs,
    const float* __restrict__ bcv,
    const float* __restrict__ alog_l, const float* __restrict__ dsk_l,
    float* __restrict__ yg)
{
    __shared__ float s5[5*128];
    float* sdt = s5;        float* su2 = s5 + 128;
    float* sz2 = s5 + 256;  float* sB  = s5 + 384;  float* sC = s5 + 512;
    int tid = threadIdx.x;
    int s  = tid & 15, dl = tid >> 4;
    int d0 = blockIdx.x * 16;
    int d  = d0 + dl;
    float a_ds = -__expf(alog_l[d*16 + s]);
    float dskv = dsk_l[d];
    float hst = 0.0f;
    for (int t0 = 0; t0 < SEQ; t0 += 8) {
        __syncthreads();
        if (tid < 128) {
            int tt = tid >> 4, j = tid & 15;
            int t = t0 + tt;
            sdt[tt*16+j] = dt[t*512 + d0 + j];
            su2[tt*16+j] = u [t*512 + d0 + j];
            sz2[tt*16+j] = zs[t*512 + d0 + j];
        } else {
            int q = tid - 128;
            int tt = q >> 4, j = q & 15;
            int t = t0 + tt;
            sB[tt*16+j] = bcv[t*32 + j];
            sC[tt*16+j] = bcv[t*32 + 16 + j];
        }
        __syncthreads();
        #pragma unroll
        for (int tt = 0; tt < 8; ++tt) {
            float dtvv = sdt[tt*16+dl];
            float uvv  = su2[tt*16+dl];
            hst = __expf(dtvv * a_ds) * hst + dtvv * uvv * sB[tt*16+s];
            float p = hst * sC[tt*16+s];
            p += __shfl_xor(p, 1);
            p += __shfl_xor(p, 2);
            p += __shfl_xor(p, 4);
            p += __shfl_xor(p, 8);
            if (s == 0) {
                float y = p + uvv * dskv;
                yg[(t0+tt)*512 + d] = y * sz2[tt*16+dl];
            }
        }
    }
}

// ---------------- head GEMM via bf16 MFMA: out(128,32000) = AH @ emb^T + hb ----------------
__global__ __launch_bounds__(256) void head_mfma_kernel(
    const hbf* __restrict__ AHb, const hbf* __restrict__ Eb,
    const float* __restrict__ hb, float* __restrict__ out)
{
    int tid = threadIdx.x;
    int lane = tid & 63;
    int wv = tid >> 6;
    int mbase = blockIdx.y * 16;
    int nbase = blockIdx.x * 64 + wv * 16;
    int m = mbase + (lane & 15);
    int n = nbase + (lane & 15);
    int k0 = (lane >> 4) * 8;
    const __bf16* Ap = (const __bf16*)AHb + m*256 + k0;
    const __bf16* Bp = (const __bf16*)Eb + (size_t)n*256 + k0;
    f32x4 acc = {0.0f, 0.0f, 0.0f, 0.0f};
    #pragma unroll
    for (int kb = 0; kb < 256; kb += 32) {
        bf16x8 a  = *(const bf16x8*)(Ap + kb);
        bf16x8 bb = *(const bf16x8*)(Bp + kb);
        acc = __builtin_amdgcn_mfma_f32_16x16x32_bf16(a, bb, acc, 0, 0, 0);
    }
    int col = lane & 15;
    int rq = lane >> 4;
    float bias = hb[nbase + col];
    #pragma unroll
    for (int i = 0; i < 4; ++i)
        out[(size_t)(mbase + rq*4 + i)*NVOCAB + nbase + col] = acc[i] + bias;
}

// ---------------- launch (16 nodes) ----------------
extern "C" void kernel_launch(void* const* d_in, const int* in_sizes, int n_in,
                              void* d_out, int out_size, void* d_ws, size_t ws_size,
                              hipStream_t stream)
{
    const int*   xin = (const int*)d_in[0];
    const float* emb = (const float*)d_in[1];
    const float* n1w = (const float*)d_in[2];
    const float* n1b = (const float*)d_in[3];
    const float* n2w = (const float*)d_in[4];
    const float* n2b = (const float*)d_in[5];
    const float* ipw = (const float*)d_in[6];
    const float* cw  = (const float*)d_in[7];
    const float* cb  = (const float*)d_in[8];
    const float* xpw = (const float*)d_in[9];
    const float* dpw = (const float*)d_in[10];
    const float* dpb = (const float*)d_in[11];
    const float* alog= (const float*)d_in[12];
    const float* dsk = (const float*)d_in[13];
    const float* opw = (const float*)d_in[14];
    const float* aiw = (const float*)d_in[15];
    const float* aib = (const float*)d_in[16];
    const float* aow = (const float*)d_in[17];
    const float* aob = (const float*)d_in[18];
    const float* nfw = (const float*)d_in[19];
    const float* nfb = (const float*)d_in[20];
    const float* hb  = (const float*)d_in[21];
    float* ws  = (float*)d_ws;
    float* out = (float*)d_out;

    hbf* AHb = (hbf*)(ws + O_AH);
    hbf* Eb  = (hbf*)(ws + O_EB);

    cvt_emb_kernel<<<2000, 256, 0, stream>>>(emb, Eb);
    cvt_w_kernel<<<1024, 256, 0, stream>>>(ipw, opw, aiw, aow, ws);

    for (int i = 0; i <= 6; ++i) {
        int ka = i <= 5 ? i : 5;          // KA layer (unused when i==6)
        int kc = i >= 1 ? i - 1 : 0;      // KC layer (unused when i==0)
        const float* hin  = (i % 2 == 0) ? ws + O_HA : ws + O_HB;
        float*       hout = (i % 2 == 0) ? ws + O_HB : ws + O_HA;
        rowk_kernel<<<128, 512, 0, stream>>>(
            xin, emb,
            n1w + ka*256, n1b + ka*256,
            n2w + kc*256, n2b + kc*256,
            (hbf*)(ws + O_WIP) + (size_t)ka*1024*256,
            cw + (size_t)ka*512*4, cb + ka*512,
            xpw + (size_t)ka*48*512, dpw + (size_t)ka*512*16, dpb + ka*512,
            (hbf*)(ws + O_WOP) + (size_t)kc*256*512,
            (hbf*)(ws + O_WAV) + (size_t)kc*256*256, aib + kc*768 + 512,
            (hbf*)(ws + O_WAO) + (size_t)kc*256*256, aob + kc*256,
            nfw, nfb,
            hin, hout,
            ws + O_YG, ws + O_U, ws + O_DT, ws + O_ZS, ws + O_BC, AHb,
            i);
        if (i <= 5)
            scan_kernel<<<32, 256, 0, stream>>>(
                ws + O_DT, ws + O_U, ws + O_ZS, ws + O_BC,
                alog + (size_t)i*512*16, dsk + i*512, ws + O_YG);
    }
    head_mfma_kernel<<<dim3(NVOCAB/64, SEQ/16), 256, 0, stream>>>(AHb, Eb, hb, out);
}